// Round 1
// baseline (872.660 us; speedup 1.0000x reference)
//
#include <hip/hip_runtime.h>
#include <math.h>

namespace {
constexpr int kB = 2;
constexpr int kS = 1024;
constexpr int kHQ = 32;
constexpr int kHKV = 8;
constexpr int kD = 128;
constexpr int kHalf = 64;
constexpr int kQT = 32;   // q rows per block
constexpr int kKT = 32;   // k rows per tile
constexpr float kScale = 0.08838834764831845f;   // 1/sqrt(128)
constexpr float kLog2e = 1.4426950408889634f;
constexpr float kNegInf = -1e30f;
constexpr float kFreqC = 0.20503692777194262f;   // ln(500000)/64
}

// Precompute cos/sin table: tab[pos*64 + j] = (cos(pos*f_j), sin(pos*f_j))
__global__ __launch_bounds__(256) void rope_table_k(float2* __restrict__ tab) {
  int t = blockIdx.x * 256 + threadIdx.x;      // 1024*64 entries
  int pos = t >> 6, j = t & 63;
  float ang = (float)pos * expf(-(float)j * kFreqC);
  float sn, cs;
  sincosf(ang, &sn, &cs);
  tab[t] = make_float2(cs, sn);
}

template <bool USE_TAB>
__global__ __launch_bounds__(256) void attn_k(
    const float* __restrict__ q, const float* __restrict__ k,
    const float* __restrict__ v, const float2* __restrict__ tab,
    float* __restrict__ out) {
  // Padded strides chosen for conflict-free LDS access patterns (see analysis).
  __shared__ float Qs[kQT][132];
  __shared__ float Ks[kKT][132];
  __shared__ float Vs[kKT][132];
  __shared__ float Ps[kQT][36];

  const int tid = threadIdx.x;
  const int qt = (int)gridDim.x - 1 - (int)blockIdx.x;  // long blocks first
  const int hq = blockIdx.y;
  const int b = blockIdx.z;
  const int hkv = hq >> 2;          // GQA = 4
  const int q0 = qt * kQT;

  const size_t qstr = (size_t)kHQ * kD;    // 4096
  const size_t kstr = (size_t)kHKV * kD;   // 1024
  const float* qb = q + (size_t)b * kS * qstr + (size_t)hq * kD;
  const float* kb = k + (size_t)b * kS * kstr + (size_t)hkv * kD;
  const float* vb = v + (size_t)b * kS * kstr + (size_t)hkv * kD;

  // ---- Stage Q tile with RoPE + scale (2048 (x1,x2) pairs / 256 threads) ----
#pragma unroll
  for (int it = 0; it < 8; ++it) {
    int pi = tid + it * 256;
    int row = pi >> 6, j = pi & 63;
    int pos = q0 + row;
    const float* qp = qb + (size_t)pos * qstr;
    float x1 = qp[j], x2 = qp[j + kHalf];
    float c, s;
    if (USE_TAB) {
      float2 t2 = tab[(pos << 6) + j]; c = t2.x; s = t2.y;
    } else {
      float ang = (float)pos * __expf(-(float)j * kFreqC);
      __sincosf(ang, &s, &c);
    }
    Qs[row][j]         = (x1 * c - x2 * s) * kScale;
    Qs[row][j + kHalf] = (x1 * s + x2 * c) * kScale;
  }

  const int qr = tid >> 3;   // 0..31 : q row within tile
  const int g  = tid & 7;    // 0..7  : column / dim group

  float m = kNegInf, l = 0.f;
  float4 o0 = {0,0,0,0}, o1 = {0,0,0,0}, o2 = {0,0,0,0}, o3 = {0,0,0,0};

  for (int kt = 0; kt <= qt; ++kt) {
    const int k0 = kt * kKT;

    // ---- Stage K tile with RoPE ----
#pragma unroll
    for (int it = 0; it < 8; ++it) {
      int pi = tid + it * 256;
      int row = pi >> 6, j = pi & 63;
      int pos = k0 + row;
      const float* kp = kb + (size_t)pos * kstr;
      float x1 = kp[j], x2 = kp[j + kHalf];
      float c, s;
      if (USE_TAB) {
        float2 t2 = tab[(pos << 6) + j]; c = t2.x; s = t2.y;
      } else {
        float ang = (float)pos * __expf(-(float)j * kFreqC);
        __sincosf(ang, &s, &c);
      }
      Ks[row][j]         = x1 * c - x2 * s;
      Ks[row][j + kHalf] = x1 * s + x2 * c;
    }
    // ---- Stage V tile (no RoPE) ----
#pragma unroll
    for (int it = 0; it < 4; ++it) {
      int f = (tid + it * 256) * 4;
      int row = f >> 7, col = f & 127;
      const float4 v4 = *(const float4*)(vb + (size_t)(k0 + row) * kstr + col);
      *(float4*)&Vs[row][col] = v4;
    }
    __syncthreads();

    // ---- QK^T: thread (qr,g) computes cols {g, g+8, g+16, g+24} ----
    float s0 = 0.f, s1 = 0.f, s2 = 0.f, s3 = 0.f;
#pragma unroll 8
    for (int d = 0; d < kD; d += 4) {
      float4 q4  = *(const float4*)&Qs[qr][d];
      float4 ka4 = *(const float4*)&Ks[g][d];
      float4 kb4 = *(const float4*)&Ks[g + 8][d];
      float4 kc4 = *(const float4*)&Ks[g + 16][d];
      float4 kd4 = *(const float4*)&Ks[g + 24][d];
      s0 = fmaf(q4.x, ka4.x, s0); s0 = fmaf(q4.y, ka4.y, s0);
      s0 = fmaf(q4.z, ka4.z, s0); s0 = fmaf(q4.w, ka4.w, s0);
      s1 = fmaf(q4.x, kb4.x, s1); s1 = fmaf(q4.y, kb4.y, s1);
      s1 = fmaf(q4.z, kb4.z, s1); s1 = fmaf(q4.w, kb4.w, s1);
      s2 = fmaf(q4.x, kc4.x, s2); s2 = fmaf(q4.y, kc4.y, s2);
      s2 = fmaf(q4.z, kc4.z, s2); s2 = fmaf(q4.w, kc4.w, s2);
      s3 = fmaf(q4.x, kd4.x, s3); s3 = fmaf(q4.y, kd4.y, s3);
      s3 = fmaf(q4.z, kd4.z, s3); s3 = fmaf(q4.w, kd4.w, s3);
    }

    // ---- causal mask (only the diagonal tile needs it; k0 == q0 there) ----
    if (kt == qt) {
      if (g      > qr) s0 = kNegInf;
      if (g + 8  > qr) s1 = kNegInf;
      if (g + 16 > qr) s2 = kNegInf;
      if (g + 24 > qr) s3 = kNegInf;
    }

    // ---- online softmax over the 8-lane row group ----
    float tmax = fmaxf(fmaxf(s0, s1), fmaxf(s2, s3));
    tmax = fmaxf(tmax, __shfl_xor(tmax, 1));
    tmax = fmaxf(tmax, __shfl_xor(tmax, 2));
    tmax = fmaxf(tmax, __shfl_xor(tmax, 4));
    float mnew = fmaxf(m, tmax);
    float alpha = exp2f((m - mnew) * kLog2e);
    float p0 = exp2f((s0 - mnew) * kLog2e);
    float p1 = exp2f((s1 - mnew) * kLog2e);
    float p2 = exp2f((s2 - mnew) * kLog2e);
    float p3 = exp2f((s3 - mnew) * kLog2e);
    float rsum = (p0 + p1) + (p2 + p3);
    rsum += __shfl_xor(rsum, 1);
    rsum += __shfl_xor(rsum, 2);
    rsum += __shfl_xor(rsum, 4);
    l = l * alpha + rsum;
    m = mnew;
    Ps[qr][g]      = p0;
    Ps[qr][g + 8]  = p1;
    Ps[qr][g + 16] = p2;
    Ps[qr][g + 24] = p3;
    o0.x *= alpha; o0.y *= alpha; o0.z *= alpha; o0.w *= alpha;
    o1.x *= alpha; o1.y *= alpha; o1.z *= alpha; o1.w *= alpha;
    o2.x *= alpha; o2.y *= alpha; o2.z *= alpha; o2.w *= alpha;
    o3.x *= alpha; o3.y *= alpha; o3.z *= alpha; o3.w *= alpha;
    __syncthreads();

    // ---- PV: thread (qr,g) owns dims {g*4+32*i + 0..3}, i = 0..3 ----
#pragma unroll
    for (int kk = 0; kk < kKT; kk += 4) {
      float4 p4 = *(const float4*)&Ps[qr][kk];
#define PV_STEP(E, PP)                                             \
      {                                                            \
        const float* vr = &Vs[kk + (E)][g * 4];                    \
        float4 va = *(const float4*)(vr);                          \
        float4 vb4 = *(const float4*)(vr + 32);                    \
        float4 vc4 = *(const float4*)(vr + 64);                    \
        float4 vd4 = *(const float4*)(vr + 96);                    \
        o0.x = fmaf(PP, va.x, o0.x);  o0.y = fmaf(PP, va.y, o0.y); \
        o0.z = fmaf(PP, va.z, o0.z);  o0.w = fmaf(PP, va.w, o0.w); \
        o1.x = fmaf(PP, vb4.x, o1.x); o1.y = fmaf(PP, vb4.y, o1.y);\
        o1.z = fmaf(PP, vb4.z, o1.z); o1.w = fmaf(PP, vb4.w, o1.w);\
        o2.x = fmaf(PP, vc4.x, o2.x); o2.y = fmaf(PP, vc4.y, o2.y);\
        o2.z = fmaf(PP, vc4.z, o2.z); o2.w = fmaf(PP, vc4.w, o2.w);\
        o3.x = fmaf(PP, vd4.x, o3.x); o3.y = fmaf(PP, vd4.y, o3.y);\
        o3.z = fmaf(PP, vd4.z, o3.z); o3.w = fmaf(PP, vd4.w, o3.w);\
      }
      PV_STEP(0, p4.x)
      PV_STEP(1, p4.y)
      PV_STEP(2, p4.z)
      PV_STEP(3, p4.w)
#undef PV_STEP
    }
    __syncthreads();
  }

  // ---- epilogue: out = O / l ----
  float inv = 1.f / l;
  float* ob = out + ((size_t)b * kS + q0 + qr) * qstr + (size_t)hq * kD + g * 4;
  float4 r0 = make_float4(o0.x * inv, o0.y * inv, o0.z * inv, o0.w * inv);
  float4 r1 = make_float4(o1.x * inv, o1.y * inv, o1.z * inv, o1.w * inv);
  float4 r2 = make_float4(o2.x * inv, o2.y * inv, o2.z * inv, o2.w * inv);
  float4 r3 = make_float4(o3.x * inv, o3.y * inv, o3.z * inv, o3.w * inv);
  *(float4*)(ob)      = r0;
  *(float4*)(ob + 32) = r1;
  *(float4*)(ob + 64) = r2;
  *(float4*)(ob + 96) = r3;
}

extern "C" void kernel_launch(void* const* d_in, const int* in_sizes, int n_in,
                              void* d_out, int out_size, void* d_ws, size_t ws_size,
                              hipStream_t stream) {
  const float* q = (const float*)d_in[0];
  const float* k = (const float*)d_in[1];
  const float* v = (const float*)d_in[2];
  float* out = (float*)d_out;

  dim3 grid(kS / kQT, kHQ, kB);   // (32, 32, 2)
  const size_t tab_bytes = sizeof(float2) * (size_t)kS * kHalf;  // 512 KB
  if (ws_size >= tab_bytes) {
    float2* tab = (float2*)d_ws;
    rope_table_k<<<(kS * kHalf) / 256, 256, 0, stream>>>(tab);
    attn_k<true><<<grid, 256, 0, stream>>>(q, k, v, tab, out);
  } else {
    attn_k<false><<<grid, 256, 0, stream>>>(q, k, v, nullptr, out);
  }
}

// Round 2
// 240.106 us; speedup vs baseline: 3.6345x; 3.6345x over previous
//
#include <hip/hip_runtime.h>
#include <math.h>

typedef __attribute__((ext_vector_type(4))) float f32x4;
typedef __attribute__((ext_vector_type(8))) short bf16x8;

namespace {
constexpr int kB = 2;
constexpr int kS = 1024;
constexpr int kHQ = 32;
constexpr int kHKV = 8;
constexpr int kD = 128;
constexpr int kQT = 64;   // q rows per block (16 per wave)
constexpr int kKT = 64;   // kv rows per tile
constexpr float kScale = 0.08838834764831845f;   // 1/sqrt(128)
constexpr float kLog2e = 1.4426950408889634f;
constexpr float kFreqC = 0.20503692777194262f;   // ln(500000)/64
constexpr int kKPad = 136;  // row stride (shorts) for Ks/Qs: 272B -> bank step 4
constexpr int kVPad = 72;   // row stride (shorts) for Vt/P: 144B -> bank step 4
}

__device__ inline short f2bf(float f) {  // RNE float->bf16
  union { float f; unsigned u; } c{f};
  unsigned r = c.u + 0x7fffu + ((c.u >> 16) & 1u);
  return (short)(r >> 16);
}

// tab[pos*64 + j] = (cos(pos*f_j), sin(pos*f_j))
__global__ __launch_bounds__(256) void rope_table_k(float2* __restrict__ tab) {
  int t = blockIdx.x * 256 + threadIdx.x;  // 1024*64
  int pos = t >> 6, j = t & 63;
  float ang = (float)pos * expf(-(float)j * kFreqC);
  float sn, cs;
  sincosf(ang, &sn, &cs);
  tab[t] = make_float2(cs, sn);
}

template <bool USE_TAB>
__global__ __launch_bounds__(256) void attn_k(
    const float* __restrict__ q, const float* __restrict__ k,
    const float* __restrict__ v, const float2* __restrict__ tab,
    float* __restrict__ out) {
  __shared__ short Ks[kKT][kKPad];          // K tile, RoPE'd, bf16
  __shared__ short Vt[kD][kVPad];           // V tile transposed: Vt[d][kv]
  __shared__ short Qbuf[kQT * kKPad];       // Q staging; later reused as P bufs

  const int tid = threadIdx.x;
  const int w = tid >> 6;          // wave 0..3
  const int lane = tid & 63;
  const int lrow = lane & 15;      // fragment row/col index
  const int lk8 = (lane >> 4) * 8; // fragment k-offset
  const int qt = (int)gridDim.x - 1 - (int)blockIdx.x;  // long blocks first
  const int hq = blockIdx.y;
  const int b = blockIdx.z;
  const int hkv = hq >> 2;
  const int q0 = qt * kQT;

  const float* qb = q + (size_t)b * kS * 4096 + hq * kD;
  const float* kb = k + (size_t)b * kS * 1024 + hkv * kD;
  const float* vb = v + (size_t)b * kS * 1024 + hkv * kD;

  // ---- Stage Q tile with RoPE + scale -> bf16 (64 rows x 64 pairs) ----
#pragma unroll
  for (int it = 0; it < 16; ++it) {
    int pi = tid + it * 256;
    int row = pi >> 6, j = pi & 63;
    int pos = q0 + row;
    float x1 = qb[(size_t)pos * 4096 + j];
    float x2 = qb[(size_t)pos * 4096 + j + 64];
    float c, s;
    if (USE_TAB) { float2 t2 = tab[(pos << 6) + j]; c = t2.x; s = t2.y; }
    else { float ang = (float)pos * __expf(-(float)j * kFreqC); __sincosf(ang, &s, &c); }
    Qbuf[row * kKPad + j]      = f2bf((x1 * c - x2 * s) * kScale);
    Qbuf[row * kKPad + j + 64] = f2bf((x1 * s + x2 * c) * kScale);
  }
  __syncthreads();

  // ---- Hoist this wave's Q A-fragments (16 rows x 128) to registers ----
  bf16x8 qf[4];
#pragma unroll
  for (int d = 0; d < 4; ++d)
    qf[d] = *(const bf16x8*)&Qbuf[(w * 16 + lrow) * kKPad + d * 32 + lk8];
  __syncthreads();  // everyone done reading Qbuf before it becomes P space

  short* myP = Qbuf + w * 16 * kVPad;  // per-wave P tile [16][kVPad]

  float mS[4] = {-3e38f, -3e38f, -3e38f, -3e38f};
  float lS[4] = {0.f, 0.f, 0.f, 0.f};
  f32x4 acc[8];
#pragma unroll
  for (int dt = 0; dt < 8; ++dt) acc[dt] = f32x4{0.f, 0.f, 0.f, 0.f};

  for (int kt = 0; kt <= qt; ++kt) {
    const int k0 = kt * kKT;

    // ---- Stage K tile with RoPE -> bf16 ----
#pragma unroll
    for (int it = 0; it < 16; ++it) {
      int pi = tid + it * 256;
      int row = pi >> 6, j = pi & 63;
      int pos = k0 + row;
      float x1 = kb[(size_t)pos * 1024 + j];
      float x2 = kb[(size_t)pos * 1024 + j + 64];
      float c, s;
      if (USE_TAB) { float2 t2 = tab[(pos << 6) + j]; c = t2.x; s = t2.y; }
      else { float ang = (float)pos * __expf(-(float)j * kFreqC); __sincosf(ang, &s, &c); }
      Ks[row][j]      = f2bf(x1 * c - x2 * s);
      Ks[row][j + 64] = f2bf(x1 * s + x2 * c);
    }
    // ---- Stage V tile transposed -> bf16 ----
#pragma unroll
    for (int it = 0; it < 8; ++it) {
      int f = (tid + it * 256) * 4;
      int row = f >> 7, col = f & 127;
      const float4 v4 = *(const float4*)(vb + (size_t)(k0 + row) * 1024 + col);
      Vt[col + 0][row] = f2bf(v4.x);
      Vt[col + 1][row] = f2bf(v4.y);
      Vt[col + 2][row] = f2bf(v4.z);
      Vt[col + 3][row] = f2bf(v4.w);
    }
    __syncthreads();

    // ---- QK^T: 4 col-tiles x 4 k-chunks of MFMA ----
    f32x4 sc[4];
#pragma unroll
    for (int ct = 0; ct < 4; ++ct) {
      sc[ct] = f32x4{0.f, 0.f, 0.f, 0.f};
#pragma unroll
      for (int d = 0; d < 4; ++d) {
        bf16x8 kf = *(const bf16x8*)&Ks[ct * 16 + lrow][d * 32 + lk8];
        sc[ct] = __builtin_amdgcn_mfma_f32_16x16x32_bf16(qf[d], kf, sc[ct], 0, 0, 0);
      }
    }

    // ---- causal mask on the diagonal tile (k0 == q0 here) ----
    if (kt == qt) {
#pragma unroll
      for (int ct = 0; ct < 4; ++ct) {
        int col = ct * 16 + lrow;
#pragma unroll
        for (int r = 0; r < 4; ++r) {
          int row = w * 16 + (lane >> 4) * 4 + r;
          if (col > row) sc[ct][r] = -3e38f;
        }
      }
    }

    // ---- online softmax; lane owns 4 rows (one per reg) ----
#pragma unroll
    for (int r = 0; r < 4; ++r) {
      float t = fmaxf(fmaxf(sc[0][r], sc[1][r]), fmaxf(sc[2][r], sc[3][r]));
      t = fmaxf(t, __shfl_xor(t, 1));
      t = fmaxf(t, __shfl_xor(t, 2));
      t = fmaxf(t, __shfl_xor(t, 4));
      t = fmaxf(t, __shfl_xor(t, 8));
      float mn = fmaxf(mS[r], t);
      float al = exp2f((mS[r] - mn) * kLog2e);
      float rs = 0.f;
#pragma unroll
      for (int ct = 0; ct < 4; ++ct) {
        float p = exp2f((sc[ct][r] - mn) * kLog2e);
        sc[ct][r] = p;
        rs += p;
      }
      rs += __shfl_xor(rs, 1);
      rs += __shfl_xor(rs, 2);
      rs += __shfl_xor(rs, 4);
      rs += __shfl_xor(rs, 8);
      lS[r] = lS[r] * al + rs;
      mS[r] = mn;
#pragma unroll
      for (int dt = 0; dt < 8; ++dt) acc[dt][r] *= al;
    }

    // ---- write P (C-layout) to per-wave LDS as bf16 ----
#pragma unroll
    for (int ct = 0; ct < 4; ++ct)
#pragma unroll
      for (int r = 0; r < 4; ++r)
        myP[((lane >> 4) * 4 + r) * kVPad + ct * 16 + lrow] = f2bf(sc[ct][r]);

    // ---- PV: A = P[16][64] from LDS, B = Vt fragments ----
#pragma unroll
    for (int ks = 0; ks < 2; ++ks) {
      bf16x8 pf = *(const bf16x8*)&myP[lrow * kVPad + ks * 32 + lk8];
#pragma unroll
      for (int dt = 0; dt < 8; ++dt) {
        bf16x8 vf = *(const bf16x8*)&Vt[dt * 16 + lrow][ks * 32 + lk8];
        acc[dt] = __builtin_amdgcn_mfma_f32_16x16x32_bf16(pf, vf, acc[dt], 0, 0, 0);
      }
    }
    __syncthreads();  // protect Ks/Vt before next staging
  }

  // ---- epilogue: out = acc / l ----
  float il[4];
#pragma unroll
  for (int r = 0; r < 4; ++r) il[r] = 1.f / lS[r];
  float* ob = out + ((size_t)b * kS + q0 + w * 16) * 4096 + hq * kD;
#pragma unroll
  for (int dt = 0; dt < 8; ++dt)
#pragma unroll
    for (int r = 0; r < 4; ++r)
      ob[((lane >> 4) * 4 + r) * 4096 + dt * 16 + lrow] = acc[dt][r] * il[r];
}

extern "C" void kernel_launch(void* const* d_in, const int* in_sizes, int n_in,
                              void* d_out, int out_size, void* d_ws, size_t ws_size,
                              hipStream_t stream) {
  const float* q = (const float*)d_in[0];
  const float* k = (const float*)d_in[1];
  const float* v = (const float*)d_in[2];
  float* out = (float*)d_out;

  dim3 grid(kS / kQT, kHQ, kB);  // (16, 32, 2)
  const size_t tab_bytes = sizeof(float2) * (size_t)kS * 64;  // 512 KB
  if (ws_size >= tab_bytes) {
    float2* tab = (float2*)d_ws;
    rope_table_k<<<(kS * 64) / 256, 256, 0, stream>>>(tab);
    attn_k<true><<<grid, 256, 0, stream>>>(q, k, v, tab, out);
  } else {
    attn_k<false><<<grid, 256, 0, stream>>>(q, k, v, nullptr, out);
  }
}

// Round 3
// 112.766 us; speedup vs baseline: 7.7387x; 2.1292x over previous
//
#include <hip/hip_runtime.h>
#include <math.h>

typedef __attribute__((ext_vector_type(4))) float f32x4;
typedef __attribute__((ext_vector_type(8))) short bf16x8;

namespace {
constexpr int kB = 2;
constexpr int kS = 1024;
constexpr int kHQ = 32;
constexpr int kHKV = 8;
constexpr int kD = 128;
constexpr int kQT = 64;   // q rows per block (16 per wave)
constexpr int kKT = 64;   // kv rows per tile
constexpr float kScale = 0.08838834764831845f;   // 1/sqrt(128)
constexpr float kLog2e = 1.4426950408889634f;
constexpr float kFreqC = 0.20503692777194262f;   // ln(500000)/64
constexpr int kKPad = 136;  // fallback kernel pads
constexpr int kVPad = 72;

// workspace layout (bytes)
constexpr size_t kTabOff = 0;                       // float2[1024*64] = 512 KB
constexpr size_t kQOff = 512 * 1024;                // bf16 [2][1024][32][128]
constexpr size_t kKOff = kQOff + 16777216;          // bf16 [2][8][1024][128]
constexpr size_t kVOff = kKOff + 4194304;           // bf16 [2][8][128][1024]
constexpr size_t kWsNeed = kVOff + 4194304;         // 25,690,112 B
}

__device__ inline short f2bf(float f) {  // RNE float->bf16
  union { float f; unsigned u; } c{f};
  unsigned r = c.u + 0x7fffu + ((c.u >> 16) & 1u);
  return (short)(r >> 16);
}

__device__ inline void gload16(const void* g, void* l) {
  __builtin_amdgcn_global_load_lds(
      (const __attribute__((address_space(1))) void*)g,
      (__attribute__((address_space(3))) void*)l, 16, 0, 0);
}

// tab[pos*64 + j] = (cos(pos*f_j), sin(pos*f_j))
__global__ __launch_bounds__(256) void rope_table_k(float2* __restrict__ tab) {
  int t = blockIdx.x * 256 + threadIdx.x;  // 1024*64
  int pos = t >> 6, j = t & 63;
  float ang = (float)pos * expf(-(float)j * kFreqC);
  float sn, cs;
  sincosf(ang, &sn, &cs);
  tab[t] = make_float2(cs, sn);
}

// Prepass: RoPE Q (scaled) and K into bf16. One thread = 4 (x1,x2) pairs.
__global__ __launch_bounds__(256) void rope_qk_k(
    const float* __restrict__ q, const float* __restrict__ k,
    const float2* __restrict__ tab, short* __restrict__ Qp,
    short* __restrict__ Kp) {
  int gt = blockIdx.x * 256 + threadIdx.x;
  const float* src;
  short* dst;
  size_t sidx, didx;
  int s, j;
  float sc;
  if (gt < 1048576) {  // Q part: [b][s][h=32][j4=16]
    j = (gt & 15) * 4;
    int h = (gt >> 4) & 31;
    s = (gt >> 9) & 1023;
    int b = gt >> 19;
    sidx = ((size_t)b * 1024 + s) * 4096 + h * 128 + j;
    didx = (((size_t)b * 1024 + s) * 32 + h) * 128 + j;
    src = q; dst = Qp; sc = kScale;
  } else {             // K part: [b][s][h=8][j4=16]
    int t2 = gt - 1048576;
    j = (t2 & 15) * 4;
    int h = (t2 >> 4) & 7;
    s = (t2 >> 7) & 1023;
    int b = t2 >> 17;
    sidx = ((size_t)b * 1024 + s) * 1024 + h * 128 + j;
    didx = (((size_t)b * 8 + h) * 1024 + s) * 128 + j;
    src = k; dst = Kp; sc = 1.0f;
  }
  float4 x1 = *(const float4*)&src[sidx];
  float4 x2 = *(const float4*)&src[sidx + 64];
  float4 t0 = *(const float4*)&tab[s * 64 + j];      // c0 s0 c1 s1
  float4 t1 = *(const float4*)&tab[s * 64 + j + 2];  // c2 s2 c3 s3
  short4 y1, y2;
  y1.x = f2bf((x1.x * t0.x - x2.x * t0.y) * sc);
  y2.x = f2bf((x1.x * t0.y + x2.x * t0.x) * sc);
  y1.y = f2bf((x1.y * t0.z - x2.y * t0.w) * sc);
  y2.y = f2bf((x1.y * t0.w + x2.y * t0.z) * sc);
  y1.z = f2bf((x1.z * t1.x - x2.z * t1.y) * sc);
  y2.z = f2bf((x1.z * t1.y + x2.z * t1.x) * sc);
  y1.w = f2bf((x1.w * t1.x * 0.f + x1.w * t1.z * 1.f - x2.w * t1.w) * sc);  // keep simple below
  y1.w = f2bf((x1.w * t1.z - x2.w * t1.w) * sc);
  y2.w = f2bf((x1.w * t1.w + x2.w * t1.z) * sc);
  *(short4*)&dst[didx] = y1;
  *(short4*)&dst[didx + 64] = y2;
}

// Prepass: V transpose to [b][hkv][d][s] bf16. Block: 64s x 64d tile.
__global__ __launch_bounds__(256) void v_tr_k(const float* __restrict__ v,
                                              short* __restrict__ Vp) {
  __shared__ float Tl[64][68];
  int blk = blockIdx.x;
  int bh = blk >> 5;            // 0..15 = b*8+h
  int rem = blk & 31;
  int s0 = (rem >> 1) * 64;
  int d0 = (rem & 1) * 64;
  int t = threadIdx.x;
#pragma unroll
  for (int i = 0; i < 4; ++i) {
    int srow = i * 16 + (t >> 4);
    int scol = (t & 15) * 4;
    float4 x = *(const float4*)&v[((size_t)(bh >> 3) * 1024 + s0 + srow) * 1024 +
                                  (bh & 7) * 128 + d0 + scol];
    *(float4*)&Tl[srow][scol] = x;
  }
  __syncthreads();
#pragma unroll
  for (int i = 0; i < 4; ++i) {
    int drow = i * 16 + (t >> 4);
    int sq = (t & 15) * 4;
    short4 y;
    y.x = f2bf(Tl[sq + 0][drow]);
    y.y = f2bf(Tl[sq + 1][drow]);
    y.z = f2bf(Tl[sq + 2][drow]);
    y.w = f2bf(Tl[sq + 3][drow]);
    *(short4*)&Vp[((size_t)bh * 128 + d0 + drow) * 1024 + s0 + sq] = y;
  }
}

// Main attention: pre-RoPE'd bf16 operands, global_load_lds staging,
// XOR-swizzled LDS (swizzle applied on global source + on reads; rule #21).
__global__ __launch_bounds__(256) void attn_pre_k(
    const short* __restrict__ Qp, const short* __restrict__ Kp,
    const short* __restrict__ Vp, float* __restrict__ out) {
  __shared__ short Ks[kKT * kD];    // [kv=64][d=128], rows XOR-swizzled
  __shared__ short Vt[kD * kKT];    // [d=128][kv=64], rows XOR-swizzled
  __shared__ short Pb[4][16 * kVPad];

  const int tid = threadIdx.x;
  const int w = tid >> 6;
  const int lane = tid & 63;
  const int lrow = lane & 15;
  const int hi = lane >> 4;
  const int lk8 = hi * 8;
  const int qt = (int)gridDim.x - 1 - (int)blockIdx.x;  // long blocks first
  const int hq = blockIdx.y;
  const int b = blockIdx.z;
  const int hkv = hq >> 2;
  const int q0 = qt * kQT;

  const char* Kh = (const char*)(Kp + ((size_t)b * 8 + hkv) * 1024 * 128);
  const char* Vh = (const char*)(Vp + ((size_t)b * 8 + hkv) * 128 * 1024);

  // ---- Q fragments straight from global bf16 ----
  const short* Qrow =
      Qp + (((size_t)b * 1024 + q0 + w * 16 + lrow) * 32 + hq) * 128;
  bf16x8 qf[4];
#pragma unroll
  for (int d = 0; d < 4; ++d) qf[d] = *(const bf16x8*)&Qrow[d * 32 + lk8];

  short* myP = &Pb[w][0];
  float mS[4] = {-3e38f, -3e38f, -3e38f, -3e38f};
  float lS[4] = {0.f, 0.f, 0.f, 0.f};
  f32x4 acc[8];
#pragma unroll
  for (int dt = 0; dt < 8; ++dt) acc[dt] = f32x4{0.f, 0.f, 0.f, 0.f};

  for (int kt = 0; kt <= qt; ++kt) {
    const int k0 = kt * kKT;

    // ---- stage K tile: 16 x 1KB instrs, wave w issues 4 ----
#pragma unroll
    for (int ii = 0; ii < 4; ++ii) {
      int i = w * 4 + ii;
      int row = i * 4 + (lane >> 4);
      int srcb = (k0 + row) * 256 + (((lane & 15) * 16) ^ ((row & 7) << 4));
      gload16(Kh + srcb, (char*)Ks + i * 1024);
    }
    // ---- stage V tile (pre-transposed in global): 16 x 1KB, 4 per wave ----
#pragma unroll
    for (int ii = 0; ii < 4; ++ii) {
      int i = w * 4 + ii;
      int row = i * 8 + (lane >> 3);  // d-row
      int srcb = row * 2048 + k0 * 2 + (((lane & 7) * 16) ^ ((row & 7) << 4));
      gload16(Vh + srcb, (char*)Vt + i * 1024);
    }
    __syncthreads();

    // ---- QK^T ----
    f32x4 sc[4];
#pragma unroll
    for (int ct = 0; ct < 4; ++ct) {
      sc[ct] = f32x4{0.f, 0.f, 0.f, 0.f};
      int r = ct * 16 + lrow;
#pragma unroll
      for (int d = 0; d < 4; ++d) {
        bf16x8 kf = *(const bf16x8*)((const char*)Ks + r * 256 +
                                     ((d * 64 + hi * 16) ^ ((lrow & 7) << 4)));
        sc[ct] = __builtin_amdgcn_mfma_f32_16x16x32_bf16(qf[d], kf, sc[ct], 0, 0, 0);
      }
    }

    // ---- causal mask on the diagonal tile ----
    if (kt == qt) {
#pragma unroll
      for (int ct = 0; ct < 4; ++ct) {
        int col = ct * 16 + lrow;
#pragma unroll
        for (int r = 0; r < 4; ++r) {
          int row = w * 16 + hi * 4 + r;
          if (col > row) sc[ct][r] = -3e38f;
        }
      }
    }

    // ---- online softmax; lane owns 4 rows ----
#pragma unroll
    for (int r = 0; r < 4; ++r) {
      float t = fmaxf(fmaxf(sc[0][r], sc[1][r]), fmaxf(sc[2][r], sc[3][r]));
      t = fmaxf(t, __shfl_xor(t, 1));
      t = fmaxf(t, __shfl_xor(t, 2));
      t = fmaxf(t, __shfl_xor(t, 4));
      t = fmaxf(t, __shfl_xor(t, 8));
      float mn = fmaxf(mS[r], t);
      float al = exp2f((mS[r] - mn) * kLog2e);
      float rs = 0.f;
#pragma unroll
      for (int ct = 0; ct < 4; ++ct) {
        float p = exp2f((sc[ct][r] - mn) * kLog2e);
        sc[ct][r] = p;
        rs += p;
      }
      rs += __shfl_xor(rs, 1);
      rs += __shfl_xor(rs, 2);
      rs += __shfl_xor(rs, 4);
      rs += __shfl_xor(rs, 8);
      lS[r] = lS[r] * al + rs;
      mS[r] = mn;
#pragma unroll
      for (int dt = 0; dt < 8; ++dt) acc[dt][r] *= al;
    }

    // ---- P -> per-wave LDS ----
#pragma unroll
    for (int ct = 0; ct < 4; ++ct)
#pragma unroll
      for (int r = 0; r < 4; ++r)
        myP[(hi * 4 + r) * kVPad + ct * 16 + lrow] = f2bf(sc[ct][r]);

    // ---- PV ----
#pragma unroll
    for (int ks = 0; ks < 2; ++ks) {
      bf16x8 pf = *(const bf16x8*)&myP[lrow * kVPad + ks * 32 + lk8];
#pragma unroll
      for (int dt = 0; dt < 8; ++dt) {
        int rv = dt * 16 + lrow;
        bf16x8 vf = *(const bf16x8*)((const char*)Vt + rv * 128 +
                                     ((ks * 64 + hi * 16) ^ ((lrow & 7) << 4)));
        acc[dt] = __builtin_amdgcn_mfma_f32_16x16x32_bf16(pf, vf, acc[dt], 0, 0, 0);
      }
    }
    __syncthreads();
  }

  // ---- epilogue ----
  float il[4];
#pragma unroll
  for (int r = 0; r < 4; ++r) il[r] = 1.f / lS[r];
  float* ob = out + ((size_t)b * kS + q0 + w * 16) * 4096 + hq * kD;
#pragma unroll
  for (int dt = 0; dt < 8; ++dt)
#pragma unroll
    for (int r = 0; r < 4; ++r)
      ob[(hi * 4 + r) * 4096 + dt * 16 + lrow] = acc[dt][r] * il[r];
}

// ---------------- R2 fallback (small-ws path), unchanged ----------------
template <bool USE_TAB>
__global__ __launch_bounds__(256) void attn_k(
    const float* __restrict__ q, const float* __restrict__ k,
    const float* __restrict__ v, const float2* __restrict__ tab,
    float* __restrict__ out) {
  __shared__ short Ksf[kKT][kKPad];
  __shared__ short Vtf[kD][kVPad];
  __shared__ short Qbuf[kQT * kKPad];
  const int tid = threadIdx.x;
  const int w = tid >> 6;
  const int lane = tid & 63;
  const int lrow = lane & 15;
  const int lk8 = (lane >> 4) * 8;
  const int qt = (int)gridDim.x - 1 - (int)blockIdx.x;
  const int hq = blockIdx.y;
  const int b = blockIdx.z;
  const int hkv = hq >> 2;
  const int q0 = qt * kQT;
  const float* qb = q + (size_t)b * kS * 4096 + hq * kD;
  const float* kb = k + (size_t)b * kS * 1024 + hkv * kD;
  const float* vb = v + (size_t)b * kS * 1024 + hkv * kD;
#pragma unroll
  for (int it = 0; it < 16; ++it) {
    int pi = tid + it * 256;
    int row = pi >> 6, j = pi & 63;
    int pos = q0 + row;
    float x1 = qb[(size_t)pos * 4096 + j];
    float x2 = qb[(size_t)pos * 4096 + j + 64];
    float c, s;
    if (USE_TAB) { float2 t2 = tab[(pos << 6) + j]; c = t2.x; s = t2.y; }
    else { float ang = (float)pos * __expf(-(float)j * kFreqC); __sincosf(ang, &s, &c); }
    Qbuf[row * kKPad + j]      = f2bf((x1 * c - x2 * s) * kScale);
    Qbuf[row * kKPad + j + 64] = f2bf((x1 * s + x2 * c) * kScale);
  }
  __syncthreads();
  bf16x8 qf[4];
#pragma unroll
  for (int d = 0; d < 4; ++d)
    qf[d] = *(const bf16x8*)&Qbuf[(w * 16 + lrow) * kKPad + d * 32 + lk8];
  __syncthreads();
  short* myP = Qbuf + w * 16 * kVPad;
  float mS[4] = {-3e38f, -3e38f, -3e38f, -3e38f};
  float lS[4] = {0.f, 0.f, 0.f, 0.f};
  f32x4 acc[8];
#pragma unroll
  for (int dt = 0; dt < 8; ++dt) acc[dt] = f32x4{0.f, 0.f, 0.f, 0.f};
  for (int kt = 0; kt <= qt; ++kt) {
    const int k0 = kt * kKT;
#pragma unroll
    for (int it = 0; it < 16; ++it) {
      int pi = tid + it * 256;
      int row = pi >> 6, j = pi & 63;
      int pos = k0 + row;
      float x1 = kb[(size_t)pos * 1024 + j];
      float x2 = kb[(size_t)pos * 1024 + j + 64];
      float c, s;
      if (USE_TAB) { float2 t2 = tab[(pos << 6) + j]; c = t2.x; s = t2.y; }
      else { float ang = (float)pos * __expf(-(float)j * kFreqC); __sincosf(ang, &s, &c); }
      Ksf[row][j]      = f2bf(x1 * c - x2 * s);
      Ksf[row][j + 64] = f2bf(x1 * s + x2 * c);
    }
#pragma unroll
    for (int it = 0; it < 8; ++it) {
      int f = (tid + it * 256) * 4;
      int row = f >> 7, col = f & 127;
      const float4 v4 = *(const float4*)(vb + (size_t)(k0 + row) * 1024 + col);
      Vtf[col + 0][row] = f2bf(v4.x);
      Vtf[col + 1][row] = f2bf(v4.y);
      Vtf[col + 2][row] = f2bf(v4.z);
      Vtf[col + 3][row] = f2bf(v4.w);
    }
    __syncthreads();
    f32x4 sc[4];
#pragma unroll
    for (int ct = 0; ct < 4; ++ct) {
      sc[ct] = f32x4{0.f, 0.f, 0.f, 0.f};
#pragma unroll
      for (int d = 0; d < 4; ++d) {
        bf16x8 kf = *(const bf16x8*)&Ksf[ct * 16 + lrow][d * 32 + lk8];
        sc[ct] = __builtin_amdgcn_mfma_f32_16x16x32_bf16(qf[d], kf, sc[ct], 0, 0, 0);
      }
    }
    if (kt == qt) {
#pragma unroll
      for (int ct = 0; ct < 4; ++ct) {
        int col = ct * 16 + lrow;
#pragma unroll
        for (int r = 0; r < 4; ++r) {
          int row = w * 16 + (lane >> 4) * 4 + r;
          if (col > row) sc[ct][r] = -3e38f;
        }
      }
    }
#pragma unroll
    for (int r = 0; r < 4; ++r) {
      float t = fmaxf(fmaxf(sc[0][r], sc[1][r]), fmaxf(sc[2][r], sc[3][r]));
      t = fmaxf(t, __shfl_xor(t, 1));
      t = fmaxf(t, __shfl_xor(t, 2));
      t = fmaxf(t, __shfl_xor(t, 4));
      t = fmaxf(t, __shfl_xor(t, 8));
      float mn = fmaxf(mS[r], t);
      float al = exp2f((mS[r] - mn) * kLog2e);
      float rs = 0.f;
#pragma unroll
      for (int ct = 0; ct < 4; ++ct) {
        float p = exp2f((sc[ct][r] - mn) * kLog2e);
        sc[ct][r] = p;
        rs += p;
      }
      rs += __shfl_xor(rs, 1);
      rs += __shfl_xor(rs, 2);
      rs += __shfl_xor(rs, 4);
      rs += __shfl_xor(rs, 8);
      lS[r] = lS[r] * al + rs;
      mS[r] = mn;
#pragma unroll
      for (int dt = 0; dt < 8; ++dt) acc[dt][r] *= al;
    }
#pragma unroll
    for (int ct = 0; ct < 4; ++ct)
#pragma unroll
      for (int r = 0; r < 4; ++r)
        myP[((lane >> 4) * 4 + r) * kVPad + ct * 16 + lrow] = f2bf(sc[ct][r]);
#pragma unroll
    for (int ks = 0; ks < 2; ++ks) {
      bf16x8 pf = *(const bf16x8*)&myP[lrow * kVPad + ks * 32 + lk8];
#pragma unroll
      for (int dt = 0; dt < 8; ++dt) {
        bf16x8 vf = *(const bf16x8*)&Vtf[dt * 16 + lrow][ks * 32 + lk8];
        acc[dt] = __builtin_amdgcn_mfma_f32_16x16x32_bf16(pf, vf, acc[dt], 0, 0, 0);
      }
    }
    __syncthreads();
  }
  float il[4];
#pragma unroll
  for (int r = 0; r < 4; ++r) il[r] = 1.f / lS[r];
  float* ob = out + ((size_t)b * kS + q0 + w * 16) * 4096 + hq * kD;
#pragma unroll
  for (int dt = 0; dt < 8; ++dt)
#pragma unroll
    for (int r = 0; r < 4; ++r)
      ob[((lane >> 4) * 4 + r) * 4096 + dt * 16 + lrow] = acc[dt][r] * il[r];
}

extern "C" void kernel_launch(void* const* d_in, const int* in_sizes, int n_in,
                              void* d_out, int out_size, void* d_ws, size_t ws_size,
                              hipStream_t stream) {
  const float* q = (const float*)d_in[0];
  const float* k = (const float*)d_in[1];
  const float* v = (const float*)d_in[2];
  float* out = (float*)d_out;
  dim3 grid(kS / kQT, kHQ, kB);  // (16, 32, 2)

  if (ws_size >= kWsNeed) {
    float2* tab = (float2*)((char*)d_ws + kTabOff);
    short* Qp = (short*)((char*)d_ws + kQOff);
    short* Kp = (short*)((char*)d_ws + kKOff);
    short* Vp = (short*)((char*)d_ws + kVOff);
    rope_table_k<<<256, 256, 0, stream>>>(tab);
    rope_qk_k<<<5120, 256, 0, stream>>>(q, k, tab, Qp, Kp);
    v_tr_k<<<512, 256, 0, stream>>>(v, Vp);
    attn_pre_k<<<grid, 256, 0, stream>>>(Qp, Kp, Vp, out);
  } else if (ws_size >= 512 * 1024) {
    float2* tab = (float2*)d_ws;
    rope_table_k<<<256, 256, 0, stream>>>(tab);
    attn_k<true><<<grid, 256, 0, stream>>>(q, k, v, tab, out);
  } else {
    attn_k<false><<<grid, 256, 0, stream>>>(q, k, v, nullptr, out);
  }
}

// Round 4
// 79.507 us; speedup vs baseline: 10.9759x; 1.4183x over previous
//
#include <hip/hip_runtime.h>
#include <math.h>

typedef __attribute__((ext_vector_type(4))) float f32x4;
typedef __attribute__((ext_vector_type(8))) short bf16x8;

namespace {
constexpr int kB = 2;
constexpr int kS = 1024;
constexpr int kD = 128;
constexpr int kQT = 64;   // q rows per block-tile (16 per wave)
constexpr int kKT = 64;   // kv rows per tile
constexpr int kNT = kS / kQT;  // 16 q-tiles; block pairs (p, 15-p)
constexpr float kScale = 0.08838834764831845f;   // 1/sqrt(128)
constexpr float kLog2e = 1.4426950408889634f;
constexpr float kFreqC = 0.20503692777194262f;   // ln(500000)/64
constexpr int kKPad = 136;  // fallback kernel pads
constexpr int kVPad = 72;

// workspace layout (bytes)
constexpr size_t kTabOff = 0;                       // float2[1024*64] = 512 KB
constexpr size_t kQOff = 512 * 1024;                // bf16 [2][1024][32][128]
constexpr size_t kKOff = kQOff + 16777216;          // bf16 [2][8][1024][128]
constexpr size_t kVOff = kKOff + 4194304;           // bf16 [2][8][128][1024]
constexpr size_t kWsNeed = kVOff + 4194304;         // 25,690,112 B
}

#define VMCNT(n) asm volatile("s_waitcnt vmcnt(" #n ")" ::: "memory")

__device__ inline short f2bf(float f) {  // RNE float->bf16
  union { float f; unsigned u; } c{f};
  unsigned r = c.u + 0x7fffu + ((c.u >> 16) & 1u);
  return (short)(r >> 16);
}

__device__ inline void gload16(const void* g, void* l) {
  __builtin_amdgcn_global_load_lds(
      (const __attribute__((address_space(1))) void*)g,
      (__attribute__((address_space(3))) void*)l, 16, 0, 0);
}

// tab[pos*64 + j] = (cos(pos*f_j), sin(pos*f_j))
__global__ __launch_bounds__(256) void rope_table_k(float2* __restrict__ tab) {
  int t = blockIdx.x * 256 + threadIdx.x;  // 1024*64
  int pos = t >> 6, j = t & 63;
  float ang = (float)pos * expf(-(float)j * kFreqC);
  float sn, cs;
  sincosf(ang, &sn, &cs);
  tab[t] = make_float2(cs, sn);
}

// Prepass: RoPE Q (scaled) and K into bf16. One thread = 4 (x1,x2) pairs.
__global__ __launch_bounds__(256) void rope_qk_k(
    const float* __restrict__ q, const float* __restrict__ k,
    const float2* __restrict__ tab, short* __restrict__ Qp,
    short* __restrict__ Kp) {
  int gt = blockIdx.x * 256 + threadIdx.x;
  const float* src;
  short* dst;
  size_t sidx, didx;
  int s, j;
  float sc;
  if (gt < 1048576) {  // Q part: [b][s][h=32][j4=16]
    j = (gt & 15) * 4;
    int h = (gt >> 4) & 31;
    s = (gt >> 9) & 1023;
    int b = gt >> 19;
    sidx = ((size_t)b * 1024 + s) * 4096 + h * 128 + j;
    didx = (((size_t)b * 1024 + s) * 32 + h) * 128 + j;
    src = q; dst = Qp; sc = kScale;
  } else {             // K part: [b][s][h=8][j4=16]
    int t2 = gt - 1048576;
    j = (t2 & 15) * 4;
    int h = (t2 >> 4) & 7;
    s = (t2 >> 7) & 1023;
    int b = t2 >> 17;
    sidx = ((size_t)b * 1024 + s) * 1024 + h * 128 + j;
    didx = (((size_t)b * 8 + h) * 1024 + s) * 128 + j;
    src = k; dst = Kp; sc = 1.0f;
  }
  float4 x1 = *(const float4*)&src[sidx];
  float4 x2 = *(const float4*)&src[sidx + 64];
  float4 t0 = *(const float4*)&tab[s * 64 + j];      // c0 s0 c1 s1
  float4 t1 = *(const float4*)&tab[s * 64 + j + 2];  // c2 s2 c3 s3
  short4 y1, y2;
  y1.x = f2bf((x1.x * t0.x - x2.x * t0.y) * sc);
  y2.x = f2bf((x1.x * t0.y + x2.x * t0.x) * sc);
  y1.y = f2bf((x1.y * t0.z - x2.y * t0.w) * sc);
  y2.y = f2bf((x1.y * t0.w + x2.y * t0.z) * sc);
  y1.z = f2bf((x1.z * t1.x - x2.z * t1.y) * sc);
  y2.z = f2bf((x1.z * t1.y + x2.z * t1.x) * sc);
  y1.w = f2bf((x1.w * t1.z - x2.w * t1.w) * sc);
  y2.w = f2bf((x1.w * t1.w + x2.w * t1.z) * sc);
  *(short4*)&dst[didx] = y1;
  *(short4*)&dst[didx + 64] = y2;
}

// Prepass: V transpose to [b][hkv][d][s] bf16. Block: 64s x 64d tile.
__global__ __launch_bounds__(256) void v_tr_k(const float* __restrict__ v,
                                              short* __restrict__ Vp) {
  __shared__ float Tl[64][68];
  int blk = blockIdx.x;
  int bh = blk >> 5;            // 0..15 = b*8+h
  int rem = blk & 31;
  int s0 = (rem >> 1) * 64;
  int d0 = (rem & 1) * 64;
  int t = threadIdx.x;
#pragma unroll
  for (int i = 0; i < 4; ++i) {
    int srow = i * 16 + (t >> 4);
    int scol = (t & 15) * 4;
    float4 x = *(const float4*)&v[((size_t)(bh >> 3) * 1024 + s0 + srow) * 1024 +
                                  (bh & 7) * 128 + d0 + scol];
    *(float4*)&Tl[srow][scol] = x;
  }
  __syncthreads();
#pragma unroll
  for (int i = 0; i < 4; ++i) {
    int drow = i * 16 + (t >> 4);
    int sq = (t & 15) * 4;
    short4 y;
    y.x = f2bf(Tl[sq + 0][drow]);
    y.y = f2bf(Tl[sq + 1][drow]);
    y.z = f2bf(Tl[sq + 2][drow]);
    y.w = f2bf(Tl[sq + 3][drow]);
    *(short4*)&Vp[((size_t)bh * 128 + d0 + drow) * 1024 + s0 + sq] = y;
  }
}

// Main attention: pre-RoPE'd bf16, triangle-paired q-tiles (uniform 17 iters),
// double-buffered K/V staged via global_load_lds with counted vmcnt + raw
// s_barrier 2-phase pipeline. XOR-swizzled LDS (swizzle on global source +
// on reads; rule #21).
__global__ __launch_bounds__(256) void attn_pre_k(
    const short* __restrict__ Qp, const short* __restrict__ Kp,
    const short* __restrict__ Vp, float* __restrict__ out) {
  __shared__ char KV[2][32768];          // per buf: K [64][128] | Vt [128][64]
  __shared__ short Pb[4][16 * kVPad];    // per-wave P tile

  const int tid = threadIdx.x;
  const int w = tid >> 6;
  const int lane = tid & 63;
  const int lrow = lane & 15;
  const int hi = lane >> 4;
  const int lk8 = hi * 8;
  const int pair = blockIdx.x;           // 0..7
  const int hq = blockIdx.y;
  const int b = blockIdx.z;
  const int hkv = hq >> 2;

  const char* Kh = (const char*)(Kp + ((size_t)b * 8 + hkv) * 1024 * 128);
  const char* Vh = (const char*)(Vp + ((size_t)b * 8 + hkv) * 128 * 1024);
  short* myP = &Pb[w][0];

  // stage one 64-row K tile + 64-col Vt tile (8 gload16 per thread)
#define STAGE_TILE(k0_, dstbuf_)                                            \
  {                                                                         \
    char* Kd = KV[dstbuf_];                                                 \
    char* Vd = KV[dstbuf_] + 16384;                                         \
    _Pragma("unroll") for (int ii = 0; ii < 4; ++ii) {                      \
      int i = w * 4 + ii;                                                   \
      int row = i * 4 + (lane >> 4);                                        \
      int srcb = ((k0_) + row) * 256 + (((lane & 15) * 16) ^ ((row & 7) << 4)); \
      gload16(Kh + srcb, Kd + i * 1024);                                    \
    }                                                                       \
    _Pragma("unroll") for (int ii = 0; ii < 4; ++ii) {                      \
      int i = w * 4 + ii;                                                   \
      int row = i * 8 + (lane >> 3);                                        \
      int srcb = row * 2048 + (k0_)*2 + (((lane & 7) * 16) ^ ((row & 7) << 4)); \
      gload16(Vh + srcb, Vd + i * 1024);                                    \
    }                                                                       \
  }

#pragma unroll
  for (int half = 0; half < 2; ++half) {
    const int qt = half ? (kNT - 1 - pair) : pair;
    const int q0 = qt * kQT;

    // Q fragments straight from global bf16
    const short* Qrow =
        Qp + (((size_t)b * 1024 + q0 + w * 16 + lrow) * 32 + hq) * 128;
    bf16x8 qf[4];
#pragma unroll
    for (int d = 0; d < 4; ++d) qf[d] = *(const bf16x8*)&Qrow[d * 32 + lk8];

    float mS[4] = {-3e38f, -3e38f, -3e38f, -3e38f};
    float lS[4] = {0.f, 0.f, 0.f, 0.f};
    f32x4 acc[8];
#pragma unroll
    for (int dt = 0; dt < 8; ++dt) acc[dt] = f32x4{0.f, 0.f, 0.f, 0.f};

    STAGE_TILE(0, 0);  // prologue
    int buf = 0;

    for (int t = 0; t <= qt; ++t) {
      if (t < qt) {
        STAGE_TILE((t + 1) * kKT, buf ^ 1);
        VMCNT(8);   // tile-t loads done; tile-(t+1)'s 8 stay in flight
      } else {
        VMCNT(0);
      }
      __builtin_amdgcn_sched_barrier(0);
      __builtin_amdgcn_s_barrier();
      __builtin_amdgcn_sched_barrier(0);

      const char* KsB = KV[buf];
      const char* VtB = KV[buf] + 16384;

      // ---- QK^T ----
      f32x4 sc[4];
#pragma unroll
      for (int ct = 0; ct < 4; ++ct) {
        sc[ct] = f32x4{0.f, 0.f, 0.f, 0.f};
        int r = ct * 16 + lrow;
#pragma unroll
        for (int d = 0; d < 4; ++d) {
          bf16x8 kf = *(const bf16x8*)(KsB + r * 256 +
                                       ((d * 64 + hi * 16) ^ ((lrow & 7) << 4)));
          sc[ct] = __builtin_amdgcn_mfma_f32_16x16x32_bf16(qf[d], kf, sc[ct], 0, 0, 0);
        }
      }

      // ---- causal mask on the diagonal tile ----
      if (t == qt) {
#pragma unroll
        for (int ct = 0; ct < 4; ++ct) {
          int col = ct * 16 + lrow;
#pragma unroll
          for (int r = 0; r < 4; ++r) {
            int row = w * 16 + hi * 4 + r;
            if (col > row) sc[ct][r] = -3e38f;
          }
        }
      }

      // ---- online softmax; lane owns 4 rows ----
#pragma unroll
      for (int r = 0; r < 4; ++r) {
        float tm = fmaxf(fmaxf(sc[0][r], sc[1][r]), fmaxf(sc[2][r], sc[3][r]));
        tm = fmaxf(tm, __shfl_xor(tm, 1));
        tm = fmaxf(tm, __shfl_xor(tm, 2));
        tm = fmaxf(tm, __shfl_xor(tm, 4));
        tm = fmaxf(tm, __shfl_xor(tm, 8));
        float mn = fmaxf(mS[r], tm);
        float al = exp2f((mS[r] - mn) * kLog2e);
        float rs = 0.f;
#pragma unroll
        for (int ct = 0; ct < 4; ++ct) {
          float p = exp2f((sc[ct][r] - mn) * kLog2e);
          sc[ct][r] = p;
          rs += p;
        }
        rs += __shfl_xor(rs, 1);
        rs += __shfl_xor(rs, 2);
        rs += __shfl_xor(rs, 4);
        rs += __shfl_xor(rs, 8);
        lS[r] = lS[r] * al + rs;
        mS[r] = mn;
#pragma unroll
        for (int dt = 0; dt < 8; ++dt) acc[dt][r] *= al;
      }

      // ---- P -> per-wave LDS (in-wave dep only) ----
#pragma unroll
      for (int ct = 0; ct < 4; ++ct)
#pragma unroll
        for (int r = 0; r < 4; ++r)
          myP[(hi * 4 + r) * kVPad + ct * 16 + lrow] = f2bf(sc[ct][r]);

      // ---- PV ----
#pragma unroll
      for (int ks = 0; ks < 2; ++ks) {
        bf16x8 pf = *(const bf16x8*)&myP[lrow * kVPad + ks * 32 + lk8];
#pragma unroll
        for (int dt = 0; dt < 8; ++dt) {
          int rv = dt * 16 + lrow;
          bf16x8 vf = *(const bf16x8*)(VtB + rv * 128 +
                                       ((ks * 64 + hi * 16) ^ ((lrow & 7) << 4)));
          acc[dt] = __builtin_amdgcn_mfma_f32_16x16x32_bf16(pf, vf, acc[dt], 0, 0, 0);
        }
      }
      __builtin_amdgcn_sched_barrier(0);
      __builtin_amdgcn_s_barrier();   // all reads of KV[buf^1] (prev iter) done
      __builtin_amdgcn_sched_barrier(0);
      buf ^= 1;
    }

    // ---- epilogue: out = acc / l ----
    float il[4];
#pragma unroll
    for (int r = 0; r < 4; ++r) il[r] = 1.f / lS[r];
    float* ob = out + ((size_t)b * kS + q0 + w * 16) * 4096 + hq * kD;
#pragma unroll
    for (int dt = 0; dt < 8; ++dt)
#pragma unroll
      for (int r = 0; r < 4; ++r)
        ob[(hi * 4 + r) * 4096 + dt * 16 + lrow] = acc[dt][r] * il[r];
  }
#undef STAGE_TILE
}

// ---------------- R2 fallback (small-ws path) ----------------
template <bool USE_TAB>
__global__ __launch_bounds__(256) void attn_k(
    const float* __restrict__ q, const float* __restrict__ k,
    const float* __restrict__ v, const float2* __restrict__ tab,
    float* __restrict__ out) {
  __shared__ short Ksf[kKT][kKPad];
  __shared__ short Vtf[kD][kVPad];
  __shared__ short Qbuf[kQT * kKPad];
  const int tid = threadIdx.x;
  const int w = tid >> 6;
  const int lane = tid & 63;
  const int lrow = lane & 15;
  const int lk8 = (lane >> 4) * 8;
  const int qt = (int)gridDim.x - 1 - (int)blockIdx.x;
  const int hq = blockIdx.y;
  const int b = blockIdx.z;
  const int hkv = hq >> 2;
  const int q0 = qt * kQT;
  const float* qb = q + (size_t)b * kS * 4096 + hq * kD;
  const float* kb = k + (size_t)b * kS * 1024 + hkv * kD;
  const float* vb = v + (size_t)b * kS * 1024 + hkv * kD;
#pragma unroll
  for (int it = 0; it < 16; ++it) {
    int pi = tid + it * 256;
    int row = pi >> 6, j = pi & 63;
    int pos = q0 + row;
    float x1 = qb[(size_t)pos * 4096 + j];
    float x2 = qb[(size_t)pos * 4096 + j + 64];
    float c, s;
    if (USE_TAB) { float2 t2 = tab[(pos << 6) + j]; c = t2.x; s = t2.y; }
    else { float ang = (float)pos * __expf(-(float)j * kFreqC); __sincosf(ang, &s, &c); }
    Qbuf[row * kKPad + j]      = f2bf((x1 * c - x2 * s) * kScale);
    Qbuf[row * kKPad + j + 64] = f2bf((x1 * s + x2 * c) * kScale);
  }
  __syncthreads();
  bf16x8 qf[4];
#pragma unroll
  for (int d = 0; d < 4; ++d)
    qf[d] = *(const bf16x8*)&Qbuf[(w * 16 + lrow) * kKPad + d * 32 + lk8];
  __syncthreads();
  short* myP = Qbuf + w * 16 * kVPad;
  float mS[4] = {-3e38f, -3e38f, -3e38f, -3e38f};
  float lS[4] = {0.f, 0.f, 0.f, 0.f};
  f32x4 acc[8];
#pragma unroll
  for (int dt = 0; dt < 8; ++dt) acc[dt] = f32x4{0.f, 0.f, 0.f, 0.f};
  for (int kt = 0; kt <= qt; ++kt) {
    const int k0 = kt * kKT;
#pragma unroll
    for (int it = 0; it < 16; ++it) {
      int pi = tid + it * 256;
      int row = pi >> 6, j = pi & 63;
      int pos = k0 + row;
      float x1 = kb[(size_t)pos * 1024 + j];
      float x2 = kb[(size_t)pos * 1024 + j + 64];
      float c, s;
      if (USE_TAB) { float2 t2 = tab[(pos << 6) + j]; c = t2.x; s = t2.y; }
      else { float ang = (float)pos * __expf(-(float)j * kFreqC); __sincosf(ang, &s, &c); }
      Ksf[row][j]      = f2bf(x1 * c - x2 * s);
      Ksf[row][j + 64] = f2bf(x1 * s + x2 * c);
    }
#pragma unroll
    for (int it = 0; it < 8; ++it) {
      int f = (tid + it * 256) * 4;
      int row = f >> 7, col = f & 127;
      const float4 v4 = *(const float4*)(vb + (size_t)(k0 + row) * 1024 + col);
      Vtf[col + 0][row] = f2bf(v4.x);
      Vtf[col + 1][row] = f2bf(v4.y);
      Vtf[col + 2][row] = f2bf(v4.z);
      Vtf[col + 3][row] = f2bf(v4.w);
    }
    __syncthreads();
    f32x4 sc[4];
#pragma unroll
    for (int ct = 0; ct < 4; ++ct) {
      sc[ct] = f32x4{0.f, 0.f, 0.f, 0.f};
#pragma unroll
      for (int d = 0; d < 4; ++d) {
        bf16x8 kf = *(const bf16x8*)&Ksf[ct * 16 + lrow][d * 32 + lk8];
        sc[ct] = __builtin_amdgcn_mfma_f32_16x16x32_bf16(qf[d], kf, sc[ct], 0, 0, 0);
      }
    }
    if (kt == qt) {
#pragma unroll
      for (int ct = 0; ct < 4; ++ct) {
        int col = ct * 16 + lrow;
#pragma unroll
        for (int r = 0; r < 4; ++r) {
          int row = w * 16 + (lane >> 4) * 4 + r;
          if (col > row) sc[ct][r] = -3e38f;
        }
      }
    }
#pragma unroll
    for (int r = 0; r < 4; ++r) {
      float t = fmaxf(fmaxf(sc[0][r], sc[1][r]), fmaxf(sc[2][r], sc[3][r]));
      t = fmaxf(t, __shfl_xor(t, 1));
      t = fmaxf(t, __shfl_xor(t, 2));
      t = fmaxf(t, __shfl_xor(t, 4));
      t = fmaxf(t, __shfl_xor(t, 8));
      float mn = fmaxf(mS[r], t);
      float al = exp2f((mS[r] - mn) * kLog2e);
      float rs = 0.f;
#pragma unroll
      for (int ct = 0; ct < 4; ++ct) {
        float p = exp2f((sc[ct][r] - mn) * kLog2e);
        sc[ct][r] = p;
        rs += p;
      }
      rs += __shfl_xor(rs, 1);
      rs += __shfl_xor(rs, 2);
      rs += __shfl_xor(rs, 4);
      rs += __shfl_xor(rs, 8);
      lS[r] = lS[r] * al + rs;
      mS[r] = mn;
#pragma unroll
      for (int dt = 0; dt < 8; ++dt) acc[dt][r] *= al;
    }
#pragma unroll
    for (int ct = 0; ct < 4; ++ct)
#pragma unroll
      for (int r = 0; r < 4; ++r)
        myP[((lane >> 4) * 4 + r) * kVPad + ct * 16 + lrow] = f2bf(sc[ct][r]);
#pragma unroll
    for (int ks = 0; ks < 2; ++ks) {
      bf16x8 pf = *(const bf16x8*)&myP[lrow * kVPad + ks * 32 + lk8];
#pragma unroll
      for (int dt = 0; dt < 8; ++dt) {
        bf16x8 vf = *(const bf16x8*)&Vtf[dt * 16 + lrow][ks * 32 + lk8];
        acc[dt] = __builtin_amdgcn_mfma_f32_16x16x32_bf16(pf, vf, acc[dt], 0, 0, 0);
      }
    }
    __syncthreads();
  }
  float il[4];
#pragma unroll
  for (int r = 0; r < 4; ++r) il[r] = 1.f / lS[r];
  float* ob = out + ((size_t)b * kS + q0 + w * 16) * 4096 + hq * kD;
#pragma unroll
  for (int dt = 0; dt < 8; ++dt)
#pragma unroll
    for (int r = 0; r < 4; ++r)
      ob[((lane >> 4) * 4 + r) * 4096 + dt * 16 + lrow] = acc[dt][r] * il[r];
}

extern "C" void kernel_launch(void* const* d_in, const int* in_sizes, int n_in,
                              void* d_out, int out_size, void* d_ws, size_t ws_size,
                              hipStream_t stream) {
  const float* q = (const float*)d_in[0];
  const float* k = (const float*)d_in[1];
  const float* v = (const float*)d_in[2];
  float* out = (float*)d_out;

  if (ws_size >= kWsNeed) {
    float2* tab = (float2*)((char*)d_ws + kTabOff);
    short* Qp = (short*)((char*)d_ws + kQOff);
    short* Kp = (short*)((char*)d_ws + kKOff);
    short* Vp = (short*)((char*)d_ws + kVOff);
    rope_table_k<<<256, 256, 0, stream>>>(tab);
    rope_qk_k<<<5120, 256, 0, stream>>>(q, k, tab, Qp, Kp);
    v_tr_k<<<512, 256, 0, stream>>>(v, Vp);
    dim3 grid(kNT / 2, 32, kB);  // (8, 32, 2) — paired q-tiles
    attn_pre_k<<<grid, 256, 0, stream>>>(Qp, Kp, Vp, out);
  } else if (ws_size >= 512 * 1024) {
    float2* tab = (float2*)d_ws;
    rope_table_k<<<256, 256, 0, stream>>>(tab);
    dim3 grid(kNT, 32, kB);
    attn_k<true><<<grid, 256, 0, stream>>>(q, k, v, tab, out);
  } else {
    dim3 grid(kNT, 32, kB);
    attn_k<false><<<grid, 256, 0, stream>>>(q, k, v, nullptr, out);
  }
}